// Round 1
// baseline (66.408 us; speedup 1.0000x reference)
//
#include <hip/hip_runtime.h>
#include <hip/hip_bf16.h>

// MLP_small_per_feature: per-feature MLP 1 -> 64 -> 64 -> 1, F=256 features,
// B=8192 batch. Middle layer = 256 batched GEMMs (8192x64 @ 64x64) done with
// v_mfma_f32_16x16x32_bf16. One wave owns one feature f and 128 batch rows;
// w2[f] lives in registers (A-fragments) for the whole wave. No LDS.
//
// MFMA layout facts used (learn_hip m89-verified, CDNA4):
//   A (first arg):  row m = lane&15, k = (lane>>4)*8 + i   (i = 0..7)
//   B (second arg): col n = lane&15, k = (lane>>4)*8 + i
//   D/C:            col n = lane&15, row m = (lane>>4)*4 + r (r = 0..3)
// We compute D[o][brow] = mfma(A=w2 tile, B=h1 tile): lane&15 = batch row,
// so layer-3's o-reduction is 16 in-lane FMAs + shfl_xor(16) + shfl_xor(32).

namespace {

constexpr int kF = 256;
constexpr int kH = 64;
constexpr int kB = 8192;

constexpr int kPasses      = 8;                   // 16 rows per pass
constexpr int kRowsPerWave = 16 * kPasses;        // 128
constexpr int kWavesPerF   = kB / kRowsPerWave;   // 64
constexpr int kWavesPerBlk = 4;
constexpr int kThreads     = kWavesPerBlk * 64;   // 256
constexpr int kBlocks      = kF * kWavesPerF / kWavesPerBlk;  // 4096

using f32x4  = __attribute__((ext_vector_type(4))) float;
using bf16x8 = __attribute__((ext_vector_type(8))) __bf16;

__global__ __launch_bounds__(kThreads)
void mlp_pf_mfma(const float* __restrict__ x,
                 const float* __restrict__ w1,
                 const float* __restrict__ b1,
                 const float* __restrict__ w2,
                 const float* __restrict__ b2,
                 const float* __restrict__ w3,
                 const float* __restrict__ b3,
                 float* __restrict__ out)
{
  const int wid  = (int)threadIdx.x >> 6;
  const int lane = (int)threadIdx.x & 63;
  const int gw   = (int)blockIdx.x * kWavesPerBlk + wid;
  const int f    = gw / kWavesPerF;
  const int rb   = gw - f * kWavesPerF;
  const int l15  = lane & 15;
  const int lg   = lane >> 4;          // 0..3

  // ---- w2[f] -> A-operand fragments, kept in registers for all passes ----
  // o-tile t covers o in [t*16, t*16+16); this lane supplies row o = t*16+l15,
  // k slots (ks*32 + lg*8 + i), which are 8 contiguous floats of w2[f][o][.].
  bf16x8 w2frag[4][2];
  {
    const float* w2f = w2 + (size_t)f * (kH * kH);
    #pragma unroll
    for (int t = 0; t < 4; ++t) {
      const int o = t * 16 + l15;
      #pragma unroll
      for (int ks = 0; ks < 2; ++ks) {
        const float* p = w2f + o * kH + ks * 32 + lg * 8;
        const float4 lo = *reinterpret_cast<const float4*>(p);
        const float4 hi = *reinterpret_cast<const float4*>(p + 4);
        bf16x8 v;
        v[0] = (__bf16)lo.x; v[1] = (__bf16)lo.y;
        v[2] = (__bf16)lo.z; v[3] = (__bf16)lo.w;
        v[4] = (__bf16)hi.x; v[5] = (__bf16)hi.y;
        v[6] = (__bf16)hi.z; v[7] = (__bf16)hi.w;
        w2frag[t][ks] = v;
      }
    }
  }

  // ---- layer-1 params for this lane's k slots: h = ks*32 + lg*8 + i ----
  float4 w1v[2][2], b1v[2][2];
  #pragma unroll
  for (int ks = 0; ks < 2; ++ks) {
    const float* pw = w1 + f * kH + ks * 32 + lg * 8;
    const float* pb = b1 + f * kH + ks * 32 + lg * 8;
    w1v[ks][0] = *reinterpret_cast<const float4*>(pw);
    w1v[ks][1] = *reinterpret_cast<const float4*>(pw + 4);
    b1v[ks][0] = *reinterpret_cast<const float4*>(pb);
    b1v[ks][1] = *reinterpret_cast<const float4*>(pb + 4);
  }

  // ---- epilogue params for this lane's o slots: o = t*16 + lg*4 + r ----
  float4 b2v[4], w3v[4];
  #pragma unroll
  for (int t = 0; t < 4; ++t) {
    b2v[t] = *reinterpret_cast<const float4*>(b2 + f * kH + t * 16 + lg * 4);
    w3v[t] = *reinterpret_cast<const float4*>(w3 + f * kH + t * 16 + lg * 4);
  }
  const float b3v = b3[f];

  // this lane's batch row (B-operand col) at pass p is rowbase + p*16
  const int rowbase = rb * kRowsPerWave + l15;

  float xv = x[(size_t)rowbase * kF + f];
  for (int p = 0; p < kPasses; ++p) {
    // issue next pass's x gather early (hide latency under MFMA/VALU)
    const int pn = (p + 1 < kPasses) ? (p + 1) : 0;
    const float xnext = x[(size_t)(rowbase + pn * 16) * kF + f];

    // ---- layer 1: h1[h] = relu(x*w1[h] + b1[h]) -> bf16 B-fragments ----
    bf16x8 h1frag[2];
    #pragma unroll
    for (int ks = 0; ks < 2; ++ks) {
      const float4 wa = w1v[ks][0], wb = w1v[ks][1];
      const float4 ba = b1v[ks][0], bb = b1v[ks][1];
      bf16x8 v;
      v[0] = (__bf16)fmaxf(xv * wa.x + ba.x, 0.f);
      v[1] = (__bf16)fmaxf(xv * wa.y + ba.y, 0.f);
      v[2] = (__bf16)fmaxf(xv * wa.z + ba.z, 0.f);
      v[3] = (__bf16)fmaxf(xv * wa.w + ba.w, 0.f);
      v[4] = (__bf16)fmaxf(xv * wb.x + bb.x, 0.f);
      v[5] = (__bf16)fmaxf(xv * wb.y + bb.y, 0.f);
      v[6] = (__bf16)fmaxf(xv * wb.z + bb.z, 0.f);
      v[7] = (__bf16)fmaxf(xv * wb.w + bb.w, 0.f);
      h1frag[ks] = v;
    }

    // ---- layer 2: D[o][brow] = w2 @ h1, 4 o-tiles x 2 k-steps ----
    f32x4 acc[4];
    #pragma unroll
    for (int t = 0; t < 4; ++t) acc[t] = f32x4{0.f, 0.f, 0.f, 0.f};
    #pragma unroll
    for (int t = 0; t < 4; ++t) {
      acc[t] = __builtin_amdgcn_mfma_f32_16x16x32_bf16(w2frag[t][0], h1frag[0], acc[t], 0, 0, 0);
      acc[t] = __builtin_amdgcn_mfma_f32_16x16x32_bf16(w2frag[t][1], h1frag[1], acc[t], 0, 0, 0);
    }

    // ---- layer 3: out = sum_o relu(acc + b2[o]) * w3[o] + b3 ----
    float partial = 0.f;
    #pragma unroll
    for (int t = 0; t < 4; ++t) {
      const float4 bb = b2v[t], ww = w3v[t];
      partial += fmaxf(acc[t][0] + bb.x, 0.f) * ww.x;
      partial += fmaxf(acc[t][1] + bb.y, 0.f) * ww.y;
      partial += fmaxf(acc[t][2] + bb.z, 0.f) * ww.z;
      partial += fmaxf(acc[t][3] + bb.w, 0.f) * ww.w;
    }
    // sum across the 4 lane-groups (each holds a disjoint set of 16 o's)
    partial += __shfl_xor(partial, 16);
    partial += __shfl_xor(partial, 32);

    if (lg == 0) {
      const int row = rowbase + p * 16;   // rowbase already includes l15
      out[(size_t)row * kF + f] = partial + b3v;
    }
    xv = xnext;
  }
}

}  // namespace

extern "C" void kernel_launch(void* const* d_in, const int* in_sizes, int n_in,
                              void* d_out, int out_size, void* d_ws, size_t ws_size,
                              hipStream_t stream) {
  const float* x  = (const float*)d_in[0];
  const float* w1 = (const float*)d_in[1];
  const float* b1 = (const float*)d_in[2];
  const float* w2 = (const float*)d_in[3];
  const float* b2 = (const float*)d_in[4];
  const float* w3 = (const float*)d_in[5];
  const float* b3 = (const float*)d_in[6];
  float* out = (float*)d_out;

  hipLaunchKernelGGL(mlp_pf_mfma, dim3(kBlocks), dim3(kThreads), 0, stream,
                     x, w1, b1, w2, b2, w3, b3, out);
}

// Round 2
// 63.241 us; speedup vs baseline: 1.0501x; 1.0501x over previous
//
#include <hip/hip_runtime.h>
#include <hip/hip_bf16.h>

// MLP_small_per_feature: per-feature MLP 1 -> 64 -> 64 -> 1, F=256, B=8192.
// v2: latency-bound fix. One wave = one feature f x 128 batch rows (8 passes
// of 16). All 8 x-gathers preloaded at wave start; b2 folded into MFMA C;
// packed f32x4 VALU; tree reduce; one full-wave store per 4 passes.
//
// MFMA 16x16x32_bf16 layout (verified in round 1, absmax 0.031):
//   A: row m = lane&15, k = (lane>>4)*8 + i
//   B: col n = lane&15, k = (lane>>4)*8 + i
//   C/D: col n = lane&15, row m = (lane>>4)*4 + r

namespace {

constexpr int kF = 256;
constexpr int kH = 64;
constexpr int kPasses      = 8;                    // 16 rows per pass
constexpr int kRowsPerWave = 16 * kPasses;         // 128
constexpr int kWavesPerF   = 64;                   // 8192/128
constexpr int kWavesPerBlk = 4;
constexpr int kThreads     = kWavesPerBlk * 64;    // 256
constexpr int kBlocks      = kF * kWavesPerF / kWavesPerBlk;  // 4096

using f32x4  = __attribute__((ext_vector_type(4))) float;
using bf16x4 = __attribute__((ext_vector_type(4))) __bf16;
using bf16x8 = __attribute__((ext_vector_type(8))) __bf16;

__global__ __launch_bounds__(kThreads)
void mlp_pf_mfma2(const float* __restrict__ x,
                  const float* __restrict__ w1,
                  const float* __restrict__ b1,
                  const float* __restrict__ w2,
                  const float* __restrict__ b2,
                  const float* __restrict__ w3,
                  const float* __restrict__ b3,
                  float* __restrict__ out)
{
  const int wid  = (int)threadIdx.x >> 6;
  const int lane = (int)threadIdx.x & 63;
  const int gw   = (int)blockIdx.x * kWavesPerBlk + wid;
  const int f    = gw >> 6;            // gw / kWavesPerF
  const int rb   = gw & 63;
  const int l15  = lane & 15;
  const int lg   = lane >> 4;          // 0..3

  const int rowbase = rb * kRowsPerWave + l15;

  // ---- ALL x gathers issued up front (the round-1 latency pole) ----
  float xv[kPasses];
  #pragma unroll
  for (int p = 0; p < kPasses; ++p)
    xv[p] = x[(rowbase + p * 16) * kF + f];

  // ---- w2[f] -> A fragments (registers, reused all passes) ----
  bf16x8 w2frag[4][2];
  {
    const float* w2f = w2 + f * (kH * kH);
    #pragma unroll
    for (int t = 0; t < 4; ++t) {
      const int o = t * 16 + l15;
      #pragma unroll
      for (int ks = 0; ks < 2; ++ks) {
        const float* p = w2f + o * kH + ks * 32 + lg * 8;
        const f32x4 lo = *reinterpret_cast<const f32x4*>(p);
        const f32x4 hi = *reinterpret_cast<const f32x4*>(p + 4);
        w2frag[t][ks] = __builtin_shufflevector(
            __builtin_convertvector(lo, bf16x4),
            __builtin_convertvector(hi, bf16x4), 0, 1, 2, 3, 4, 5, 6, 7);
      }
    }
  }

  // ---- layer-1 params, lane's k slots h = ks*32 + lg*8 + i ----
  f32x4 w1v[2][2], b1v[2][2];
  #pragma unroll
  for (int ks = 0; ks < 2; ++ks) {
    const float* pw = w1 + f * kH + ks * 32 + lg * 8;
    const float* pb = b1 + f * kH + ks * 32 + lg * 8;
    w1v[ks][0] = *reinterpret_cast<const f32x4*>(pw);
    w1v[ks][1] = *reinterpret_cast<const f32x4*>(pw + 4);
    b1v[ks][0] = *reinterpret_cast<const f32x4*>(pb);
    b1v[ks][1] = *reinterpret_cast<const f32x4*>(pb + 4);
  }

  // ---- epilogue params, lane's o slots o = t*16 + lg*4 + r ----
  // b2 in C/D layout -> used directly as the MFMA C operand.
  f32x4 b2c[4], w3v[4];
  #pragma unroll
  for (int t = 0; t < 4; ++t) {
    b2c[t] = *reinterpret_cast<const f32x4*>(b2 + f * kH + t * 16 + lg * 4);
    w3v[t] = *reinterpret_cast<const f32x4*>(w3 + f * kH + t * 16 + lg * 4);
  }
  const float b3v = b3[f];

  const f32x4 zero4 = {0.f, 0.f, 0.f, 0.f};
  float keep = 0.f;

  #pragma unroll
  for (int p = 0; p < kPasses; ++p) {
    // ---- layer 1: h1 = relu(x*w1 + b1) -> bf16 B-fragments (packed f32x4) ----
    bf16x8 h1frag[2];
    #pragma unroll
    for (int ks = 0; ks < 2; ++ks) {
      f32x4 a = w1v[ks][0] * xv[p] + b1v[ks][0];
      f32x4 b = w1v[ks][1] * xv[p] + b1v[ks][1];
      a = __builtin_elementwise_max(a, zero4);
      b = __builtin_elementwise_max(b, zero4);
      h1frag[ks] = __builtin_shufflevector(
          __builtin_convertvector(a, bf16x4),
          __builtin_convertvector(b, bf16x4), 0, 1, 2, 3, 4, 5, 6, 7);
    }

    // ---- layer 2 (C init = b2) + layer 3 epilogue, per o-tile ----
    f32x4 p4 = zero4;
    #pragma unroll
    for (int t = 0; t < 4; ++t) {
      f32x4 acc = __builtin_amdgcn_mfma_f32_16x16x32_bf16(
          w2frag[t][0], h1frag[0], b2c[t], 0, 0, 0);
      acc = __builtin_amdgcn_mfma_f32_16x16x32_bf16(
          w2frag[t][1], h1frag[1], acc, 0, 0, 0);
      const f32x4 r = __builtin_elementwise_max(acc, zero4);
      p4 += r * w3v[t];
    }

    // ---- tree reduce (4-deep, not 16-deep serial) + cross-group sum ----
    float s = (p4[0] + p4[1]) + (p4[2] + p4[3]);
    s += __shfl_xor(s, 16);
    s += __shfl_xor(s, 32);

    // lane-group lg keeps pass (quad*4 + lg); one full-wave store per quad
    keep = (lg == (p & 3)) ? s : keep;
    if ((p & 3) == 3) {
      const int row = rb * kRowsPerWave + (p >> 2) * 64 + lane;
      out[row * kF + f] = keep + b3v;
    }
  }
}

}  // namespace

extern "C" void kernel_launch(void* const* d_in, const int* in_sizes, int n_in,
                              void* d_out, int out_size, void* d_ws, size_t ws_size,
                              hipStream_t stream) {
  const float* x  = (const float*)d_in[0];
  const float* w1 = (const float*)d_in[1];
  const float* b1 = (const float*)d_in[2];
  const float* w2 = (const float*)d_in[3];
  const float* b2 = (const float*)d_in[4];
  const float* w3 = (const float*)d_in[5];
  const float* b3 = (const float*)d_in[6];
  float* out = (float*)d_out;

  hipLaunchKernelGGL(mlp_pf_mfma2, dim3(kBlocks), dim3(kThreads), 0, stream,
                     x, w1, b1, w2, b2, w3, b3, out);
}

// Round 3
// 47.247 us; speedup vs baseline: 1.4055x; 1.3385x over previous
//
#include <hip/hip_runtime.h>
#include <hip/hip_bf16.h>

// MLP_small_per_feature: per-feature MLP 1 -> 64 -> 64 -> 1, F=256, B=8192.
// v3: kill scattered-gather TA traffic. Block = 4 waves = 4 features x 512
// rows. x staged coalesced + transposed into LDS; w2 staged coalesced ->
// bf16 XOR-swizzled LDS -> fragment ds_reads (once per wave, reused over 32
// passes); outputs exchanged through LDS and stored as float4 per row.
//
// MFMA 16x16x32_bf16 layout (verified rounds 1-2, absmax 0.031):
//   A: row m = lane&15, k = (lane>>4)*8 + i
//   B: col n = lane&15, k = (lane>>4)*8 + i
//   C/D: col n = lane&15, row m = (lane>>4)*4 + r

namespace {

constexpr int kF = 256;
constexpr int kH = 64;
constexpr int kB = 8192;

constexpr int kFPB     = 4;               // features per block (one per wave)
constexpr int kRPB     = 512;             // rows per block
constexpr int kThreads = 256;             // 4 waves
constexpr int kFG      = kF / kFPB;       // 64 feature groups
constexpr int kRG      = kB / kRPB;       // 16 row groups
constexpr int kBlocks  = kFG * kRG;       // 1024
constexpr int kPasses  = kRPB / 16;       // 32

using f32x4  = __attribute__((ext_vector_type(4))) float;
using bf16x4 = __attribute__((ext_vector_type(4))) __bf16;
using bf16x8 = __attribute__((ext_vector_type(8))) __bf16;

__global__ __launch_bounds__(kThreads, 3)
void mlp_pf_v3(const float* __restrict__ x,
               const float* __restrict__ w1,
               const float* __restrict__ b1,
               const float* __restrict__ w2,
               const float* __restrict__ b2,
               const float* __restrict__ w3,
               const float* __restrict__ b3,
               float* __restrict__ out)
{
  // 32 KB + 8 KB + 10 KB = 50 KB -> 3 blocks/CU
  __shared__ __bf16 w2s[kFPB][kH * kH];    // bf16, XOR-swizzled 16B chunks
  __shared__ float  xs[kFPB][kRPB];        // x tile, transposed
  __shared__ float  outb[kRPB][kFPB + 1];  // +1 pad: conflict-free exchange

  const int tid  = (int)threadIdx.x;
  const int wid  = tid >> 6;
  const int lane = tid & 63;
  const int l15  = lane & 15;
  const int lg   = lane >> 4;

  const int fg = (int)blockIdx.x & (kFG - 1);
  const int rg = (int)blockIdx.x >> 6;
  const int f  = fg * kFPB + wid;          // this wave's feature
  const int r0 = rg * kRPB;

  // ---- stage x tile (512 rows x 4 feats) coalesced, transpose into LDS ----
  #pragma unroll
  for (int rr = tid; rr < kRPB; rr += kThreads) {
    const f32x4 v = *reinterpret_cast<const f32x4*>(
        x + (size_t)(r0 + rr) * kF + fg * kFPB);
    xs[0][rr] = v[0]; xs[1][rr] = v[1]; xs[2][rr] = v[2]; xs[3][rr] = v[3];
  }

  // ---- stage w2[f] coalesced -> bf16 swizzled LDS (intra-wave) ----
  // Global: instr j, lane l reads float4 = w2[f] row (j*4 + l/16),
  // cols (l&15)*4..+4. LDS dest: row r (128 B), 16B chunk c=(l&15)>>1 at
  // swizzled slot cs = c ^ (r&7), 8B half = l&1.
  {
    const float* w2f = w2 + (size_t)f * (kH * kH);
    char* dst = (char*)&w2s[wid][0];
    #pragma unroll
    for (int j = 0; j < 16; ++j) {
      const f32x4 v = *reinterpret_cast<const f32x4*>(w2f + j * 256 + lane * 4);
      const int r    = j * 4 + (lane >> 4);
      const int c    = (lane & 15) >> 1;
      const int half = lane & 1;
      const int cs   = c ^ (r & 7);
      *reinterpret_cast<bf16x4*>(dst + r * 128 + cs * 16 + half * 8) =
          __builtin_convertvector(v, bf16x4);
    }
  }

  __syncthreads();

  // ---- w2 fragments from LDS (once; reused for all 32 passes) ----
  // Lane (l15,lg) needs row o = t*16+l15, bf16 cols ks*32+lg*8..+8
  // -> chunk c = ks*4+lg at swizzled slot c ^ (o&7).
  bf16x8 w2frag[4][2];
  {
    const char* src = (const char*)&w2s[wid][0];
    #pragma unroll
    for (int t = 0; t < 4; ++t) {
      const int o = t * 16 + l15;
      #pragma unroll
      for (int ks = 0; ks < 2; ++ks) {
        const int cs = (ks * 4 + lg) ^ (o & 7);
        w2frag[t][ks] = *reinterpret_cast<const bf16x8*>(src + o * 128 + cs * 16);
      }
    }
  }

  // ---- per-wave params (tiny, L1-resident) ----
  f32x4 w1v[2][2], b1v[2][2];
  #pragma unroll
  for (int ks = 0; ks < 2; ++ks) {
    const float* pw = w1 + f * kH + ks * 32 + lg * 8;
    const float* pb = b1 + f * kH + ks * 32 + lg * 8;
    w1v[ks][0] = *reinterpret_cast<const f32x4*>(pw);
    w1v[ks][1] = *reinterpret_cast<const f32x4*>(pw + 4);
    b1v[ks][0] = *reinterpret_cast<const f32x4*>(pb);
    b1v[ks][1] = *reinterpret_cast<const f32x4*>(pb + 4);
  }
  f32x4 b2c[4], w3v[4];
  #pragma unroll
  for (int t = 0; t < 4; ++t) {
    b2c[t] = *reinterpret_cast<const f32x4*>(b2 + f * kH + t * 16 + lg * 4);
    w3v[t] = *reinterpret_cast<const f32x4*>(w3 + f * kH + t * 16 + lg * 4);
  }
  const float b3v = b3[f];

  const f32x4 zero4 = {0.f, 0.f, 0.f, 0.f};

  #pragma unroll 4
  for (int p = 0; p < kPasses; ++p) {
    // x value for this lane's batch row (broadcast across lane groups)
    const float xv = xs[wid][p * 16 + l15];

    // ---- layer 1: h1 = relu(x*w1 + b1) -> bf16 B-fragments ----
    bf16x8 h1frag[2];
    #pragma unroll
    for (int ks = 0; ks < 2; ++ks) {
      f32x4 a = w1v[ks][0] * xv + b1v[ks][0];
      f32x4 b = w1v[ks][1] * xv + b1v[ks][1];
      a = __builtin_elementwise_max(a, zero4);
      b = __builtin_elementwise_max(b, zero4);
      h1frag[ks] = __builtin_shufflevector(
          __builtin_convertvector(a, bf16x4),
          __builtin_convertvector(b, bf16x4), 0, 1, 2, 3, 4, 5, 6, 7);
    }

    // ---- layer 2 (C init = b2) + layer 3 epilogue ----
    f32x4 p4 = zero4;
    #pragma unroll
    for (int t = 0; t < 4; ++t) {
      f32x4 acc = __builtin_amdgcn_mfma_f32_16x16x32_bf16(
          w2frag[t][0], h1frag[0], b2c[t], 0, 0, 0);
      acc = __builtin_amdgcn_mfma_f32_16x16x32_bf16(
          w2frag[t][1], h1frag[1], acc, 0, 0, 0);
      const f32x4 r = __builtin_elementwise_max(acc, zero4);
      p4 += r * w3v[t];
    }

    float s = (p4[0] + p4[1]) + (p4[2] + p4[3]);
    s += __shfl_xor(s, 16);
    s += __shfl_xor(s, 32);

    if (lg == 0) outb[p * 16 + l15][wid] = s + b3v;
  }

  __syncthreads();

  // ---- coalesced-ish output: one float4 (4 features) per row ----
  #pragma unroll
  for (int rr = tid; rr < kRPB; rr += kThreads) {
    const f32x4 v = {outb[rr][0], outb[rr][1], outb[rr][2], outb[rr][3]};
    *reinterpret_cast<f32x4*>(out + (size_t)(r0 + rr) * kF + fg * kFPB) = v;
  }
}

}  // namespace

extern "C" void kernel_launch(void* const* d_in, const int* in_sizes, int n_in,
                              void* d_out, int out_size, void* d_ws, size_t ws_size,
                              hipStream_t stream) {
  const float* x  = (const float*)d_in[0];
  const float* w1 = (const float*)d_in[1];
  const float* b1 = (const float*)d_in[2];
  const float* w2 = (const float*)d_in[3];
  const float* b2 = (const float*)d_in[4];
  const float* w3 = (const float*)d_in[5];
  const float* b3 = (const float*)d_in[6];
  float* out = (float*)d_out;

  hipLaunchKernelGGL(mlp_pf_v3, dim3(kBlocks), dim3(kThreads), 0, stream,
                     x, w1, b1, w2, b2, w3, b3, out);
}

// Round 4
// 43.445 us; speedup vs baseline: 1.5286x; 1.0875x over previous
//
#include <hip/hip_runtime.h>
#include <hip/hip_bf16.h>

// MLP_small_per_feature: per-feature MLP 1 -> 64 -> 64 -> 1, F=256, B=8192.
// v4: occupancy over LDS. Block = 4 waves = 4 features x 512 rows. w2
// fragments gathered DIRECTLY from global per wave (once, amortized over 32
// passes) -- no w2 LDS staging. LDS only for x transpose + output exchange
// (18.25 KB) so all 4 blocks/CU are resident: no tail, 16 waves/CU.
//
// MFMA 16x16x32_bf16 layout (verified rounds 1-3, absmax 0.031):
//   A: row m = lane&15, k = (lane>>4)*8 + i
//   B: col n = lane&15, k = (lane>>4)*8 + i
//   C/D: col n = lane&15, row m = (lane>>4)*4 + r

namespace {

constexpr int kF = 256;
constexpr int kH = 64;
constexpr int kB = 8192;

constexpr int kFPB     = 4;               // features per block (one per wave)
constexpr int kRPB     = 512;             // rows per block
constexpr int kThreads = 256;             // 4 waves
constexpr int kFG      = kF / kFPB;       // 64 feature groups
constexpr int kRG      = kB / kRPB;       // 16 row groups
constexpr int kBlocks  = kFG * kRG;       // 1024 = 4 blocks/CU, all resident
constexpr int kPasses  = kRPB / 16;       // 32

using f32x4  = __attribute__((ext_vector_type(4))) float;
using bf16x4 = __attribute__((ext_vector_type(4))) __bf16;
using bf16x8 = __attribute__((ext_vector_type(8))) __bf16;

__global__ __launch_bounds__(kThreads, 4)
void mlp_pf_v4(const float* __restrict__ x,
               const float* __restrict__ w1,
               const float* __restrict__ b1,
               const float* __restrict__ w2,
               const float* __restrict__ b2,
               const float* __restrict__ w3,
               const float* __restrict__ b3,
               float* __restrict__ out)
{
  __shared__ float xs[kFPB][kRPB];        // 8 KB
  __shared__ float outb[kRPB][kFPB + 1];  // 10.25 KB (pad: conflict-free)

  const int tid  = (int)threadIdx.x;
  const int wid  = tid >> 6;
  const int lane = tid & 63;
  const int l15  = lane & 15;
  const int lg   = lane >> 4;

  const int fg = (int)blockIdx.x & (kFG - 1);
  const int rg = (int)blockIdx.x >> 6;
  const int f  = fg * kFPB + wid;          // this wave's feature
  const int r0 = rg * kRPB;

  // ---- w2[f] fragments straight from global (once; reused 32 passes).
  // Issued before the barrier so all waves' gathers overlap x staging.
  bf16x8 w2frag[4][2];
  {
    const float* w2f = w2 + (size_t)f * (kH * kH);
    #pragma unroll
    for (int t = 0; t < 4; ++t) {
      const int o = t * 16 + l15;
      #pragma unroll
      for (int ks = 0; ks < 2; ++ks) {
        const float* p = w2f + o * kH + ks * 32 + lg * 8;
        const f32x4 lo = *reinterpret_cast<const f32x4*>(p);
        const f32x4 hi = *reinterpret_cast<const f32x4*>(p + 4);
        w2frag[t][ks] = __builtin_shufflevector(
            __builtin_convertvector(lo, bf16x4),
            __builtin_convertvector(hi, bf16x4), 0, 1, 2, 3, 4, 5, 6, 7);
      }
    }
  }

  // ---- stage x tile (512 rows x 4 feats), transpose into LDS ----
  #pragma unroll
  for (int rr = tid; rr < kRPB; rr += kThreads) {
    const f32x4 v = *reinterpret_cast<const f32x4*>(
        x + (size_t)(r0 + rr) * kF + fg * kFPB);
    xs[0][rr] = v[0]; xs[1][rr] = v[1]; xs[2][rr] = v[2]; xs[3][rr] = v[3];
  }

  // ---- per-wave params (tiny, L1/L2-resident) ----
  f32x4 w1v[2][2], b1v[2][2];
  #pragma unroll
  for (int ks = 0; ks < 2; ++ks) {
    const float* pw = w1 + f * kH + ks * 32 + lg * 8;
    const float* pb = b1 + f * kH + ks * 32 + lg * 8;
    w1v[ks][0] = *reinterpret_cast<const f32x4*>(pw);
    w1v[ks][1] = *reinterpret_cast<const f32x4*>(pw + 4);
    b1v[ks][0] = *reinterpret_cast<const f32x4*>(pb);
    b1v[ks][1] = *reinterpret_cast<const f32x4*>(pb + 4);
  }
  f32x4 b2c[4], w3v[4];
  #pragma unroll
  for (int t = 0; t < 4; ++t) {
    b2c[t] = *reinterpret_cast<const f32x4*>(b2 + f * kH + t * 16 + lg * 4);
    w3v[t] = *reinterpret_cast<const f32x4*>(w3 + f * kH + t * 16 + lg * 4);
  }
  const float b3v = b3[f];

  __syncthreads();   // xs ready

  const f32x4 zero4 = {0.f, 0.f, 0.f, 0.f};

  #pragma unroll 4
  for (int p = 0; p < kPasses; ++p) {
    // x value for this lane's batch row (broadcast across lane groups)
    const float xv = xs[wid][p * 16 + l15];

    // ---- layer 1: h1 = relu(x*w1 + b1) -> bf16 B-fragments ----
    bf16x8 h1frag[2];
    #pragma unroll
    for (int ks = 0; ks < 2; ++ks) {
      f32x4 a = w1v[ks][0] * xv + b1v[ks][0];
      f32x4 b = w1v[ks][1] * xv + b1v[ks][1];
      a = __builtin_elementwise_max(a, zero4);
      b = __builtin_elementwise_max(b, zero4);
      h1frag[ks] = __builtin_shufflevector(
          __builtin_convertvector(a, bf16x4),
          __builtin_convertvector(b, bf16x4), 0, 1, 2, 3, 4, 5, 6, 7);
    }

    // ---- layer 2 (C init = b2) + layer 3 epilogue ----
    f32x4 p4 = zero4;
    #pragma unroll
    for (int t = 0; t < 4; ++t) {
      f32x4 acc = __builtin_amdgcn_mfma_f32_16x16x32_bf16(
          w2frag[t][0], h1frag[0], b2c[t], 0, 0, 0);
      acc = __builtin_amdgcn_mfma_f32_16x16x32_bf16(
          w2frag[t][1], h1frag[1], acc, 0, 0, 0);
      const f32x4 r = __builtin_elementwise_max(acc, zero4);
      p4 += r * w3v[t];
    }

    float s = (p4[0] + p4[1]) + (p4[2] + p4[3]);
    s += __shfl_xor(s, 16);
    s += __shfl_xor(s, 32);

    if (lg == 0) outb[p * 16 + l15][wid] = s + b3v;
  }

  __syncthreads();

  // ---- output: one float4 (4 features) per row ----
  #pragma unroll
  for (int rr = tid; rr < kRPB; rr += kThreads) {
    const f32x4 v = {outb[rr][0], outb[rr][1], outb[rr][2], outb[rr][3]};
    *reinterpret_cast<f32x4*>(out + (size_t)(r0 + rr) * kF + fg * kFPB) = v;
  }
}

}  // namespace

extern "C" void kernel_launch(void* const* d_in, const int* in_sizes, int n_in,
                              void* d_out, int out_size, void* d_ws, size_t ws_size,
                              hipStream_t stream) {
  const float* x  = (const float*)d_in[0];
  const float* w1 = (const float*)d_in[1];
  const float* b1 = (const float*)d_in[2];
  const float* w2 = (const float*)d_in[3];
  const float* b2 = (const float*)d_in[4];
  const float* w3 = (const float*)d_in[5];
  const float* b3 = (const float*)d_in[6];
  float* out = (float*)d_out;

  hipLaunchKernelGGL(mlp_pf_v4, dim3(kBlocks), dim3(kThreads), 0, stream,
                     x, w1, b1, w2, b2, w3, b3, out);
}